// Round 7
// baseline (221.521 us; speedup 1.0000x reference)
//
#include <hip/hip_runtime.h>
#include <math.h>

#define BT 1024
#define BN 1024
#define D  256
#define H  8
#define DH 32

typedef __attribute__((ext_vector_type(8))) short short8;
typedef __attribute__((ext_vector_type(4))) float f32x4;

__device__ __forceinline__ unsigned short f2bf(float x) {
  union { float f; unsigned int u; } v; v.f = x;
  unsigned int r = v.u + 0x7fffu + ((v.u >> 16) & 1u);
  return (unsigned short)(r >> 16);
}
__device__ __forceinline__ float bf2f(unsigned short u) {
  union { unsigned int u; float f; } v; v.u = ((unsigned int)u) << 16;
  return v.f;
}
__device__ __forceinline__ unsigned pack2(float a, float b) {
  return (unsigned)f2bf(a) | ((unsigned)f2bf(b) << 16);
}

// Grid-wide barrier via device-scope atomics (all 512 blocks co-resident:
// __launch_bounds__(256,2) caps VGPR<=256, LDS 2x42240<160K -> 2 blocks/CU).
__device__ __forceinline__ void grid_barrier(unsigned* bar, unsigned target) {
  __syncthreads();
  if (threadIdx.x == 0) {
    __threadfence();  // release: make prior global writes visible device-wide
    __hip_atomic_fetch_add(bar, 1u, __ATOMIC_ACQ_REL, __HIP_MEMORY_SCOPE_AGENT);
    while (__hip_atomic_load(bar, __ATOMIC_ACQUIRE, __HIP_MEMORY_SCOPE_AGENT) <
           target) {
      __builtin_amdgcn_s_sleep(8);
    }
    __threadfence();  // acquire: invalidate stale cache lines
  }
  __syncthreads();
}

// ---------------------------------------------------------------------------
// Phase-A job bodies. smem is a 42240-byte scratch reused across phases.
// ---------------------------------------------------------------------------
__device__ void job_qkv(int job, char* smem,
                        const float* __restrict__ ht, const float* __restrict__ hn,
                        const float* __restrict__ Wq, const float* __restrict__ bq,
                        const float* __restrict__ Wk, const float* __restrict__ bk,
                        const float* __restrict__ Wv, const float* __restrict__ bv,
                        unsigned short* __restrict__ Qh, unsigned short* __restrict__ Kh,
                        unsigned short* __restrict__ Vt) {
  const int gm = job >> 8;           // 0=Q, 1=K, 2=V
  const int rem = job & 255;
  const int m0 = (rem & 63) * 16;
  const int nb0 = (rem >> 6) * 64;
  const float* X = (gm == 0) ? ht : hn;
  const float* W = (gm == 0) ? Wq : (gm == 1) ? Wk : Wv;
  const float* bias = (gm == 0) ? bq : (gm == 1) ? bk : bv;

  unsigned short (*als)[264] = (unsigned short(*)[264])smem;          // 16 rows
  unsigned short (*bls)[264] = (unsigned short(*)[264])(smem + 8448); // 64 rows

  const int tid = threadIdx.x;
  const int c = (tid & 15) * 16;
  {
    int row = tid >> 4;
    const float* s = X + (size_t)(m0 + row) * D + c;
    uint4 u0, u1;
    float4 f;
    f = *(const float4*)(s + 0);  u0.x = pack2(f.x, f.y); u0.y = pack2(f.z, f.w);
    f = *(const float4*)(s + 4);  u0.z = pack2(f.x, f.y); u0.w = pack2(f.z, f.w);
    f = *(const float4*)(s + 8);  u1.x = pack2(f.x, f.y); u1.y = pack2(f.z, f.w);
    f = *(const float4*)(s + 12); u1.z = pack2(f.x, f.y); u1.w = pack2(f.z, f.w);
    *(uint4*)&als[row][c] = u0;
    *(uint4*)&als[row][c + 8] = u1;
  }
#pragma unroll
  for (int j = 0; j < 4; ++j) {
    int row = j * 16 + (tid >> 4);
    const float* s = W + (size_t)(nb0 + row) * D + c;
    uint4 u0, u1;
    float4 f;
    f = *(const float4*)(s + 0);  u0.x = pack2(f.x, f.y); u0.y = pack2(f.z, f.w);
    f = *(const float4*)(s + 4);  u0.z = pack2(f.x, f.y); u0.w = pack2(f.z, f.w);
    f = *(const float4*)(s + 8);  u1.x = pack2(f.x, f.y); u1.y = pack2(f.z, f.w);
    f = *(const float4*)(s + 12); u1.z = pack2(f.x, f.y); u1.w = pack2(f.z, f.w);
    *(uint4*)&bls[row][c] = u0;
    *(uint4*)&bls[row][c + 8] = u1;
  }
  __syncthreads();

  const int lane = tid & 63, wid = tid >> 6;
  const int quad = lane >> 4, l16 = lane & 15;
  f32x4 acc0 = {0.f, 0.f, 0.f, 0.f};
  f32x4 acc1 = {0.f, 0.f, 0.f, 0.f};
#pragma unroll
  for (int k0 = 0; k0 < 128; k0 += 32) {
    short8 a = *(const short8*)&als[l16][k0 + quad * 8];
    short8 b = *(const short8*)&bls[wid * 16 + l16][k0 + quad * 8];
    acc0 = __builtin_amdgcn_mfma_f32_16x16x32_bf16(a, b, acc0, 0, 0, 0);
  }
#pragma unroll
  for (int k0 = 128; k0 < 256; k0 += 32) {
    short8 a = *(const short8*)&als[l16][k0 + quad * 8];
    short8 b = *(const short8*)&bls[wid * 16 + l16][k0 + quad * 8];
    acc1 = __builtin_amdgcn_mfma_f32_16x16x32_bf16(a, b, acc1, 0, 0, 0);
  }
  f32x4 acc = acc0 + acc1;

  const int col = nb0 + wid * 16 + l16;
  const float bia = bias[col];
  const int h = col >> 5, d = col & 31;
  if (gm == 2) {
    uint2 o;
    o.x = pack2(acc[0] + bia, acc[1] + bia);
    o.y = pack2(acc[2] + bia, acc[3] + bia);
    *(uint2*)(Vt + (size_t)h * 32768 + (size_t)d * 1024 + m0 + quad * 4) = o;
  } else {
    unsigned short* dst = (gm == 0) ? Qh : Kh;
#pragma unroll
    for (int r = 0; r < 4; ++r) {
      int row = m0 + quad * 4 + r;
      dst[(size_t)h * 32768 + (size_t)row * 32 + d] = f2bf(acc[r] + bia);
    }
  }
}

// tagsQ layout: [rt(64)][n(1024)][quad(4)] of uchar4 (16 B per (rt,n)).
__device__ void job_tags(int local, char* smem,
                         const int* __restrict__ adj, const int* __restrict__ ety,
                         unsigned char* __restrict__ tagsQ) {
  unsigned char (*tl)[68] = (unsigned char(*)[68])smem;
  const int tid = threadIdx.x;
  const int row0 = (local >> 4) * 64;
  const int n0 = (local & 15) * 64;
#pragma unroll
  for (int j = 0; j < 4; ++j) {
    int row = j * 16 + (tid >> 4);
    int c0 = (tid & 15) * 4;
    int4 a = *(const int4*)(adj + (size_t)(row0 + row) * BN + n0 + c0);
    int4 t = *(const int4*)(ety + (size_t)(row0 + row) * BN + n0 + c0);
    tl[c0 + 0][row] = a.x ? (unsigned char)t.x : (unsigned char)2;
    tl[c0 + 1][row] = a.y ? (unsigned char)t.y : (unsigned char)2;
    tl[c0 + 2][row] = a.z ? (unsigned char)t.z : (unsigned char)2;
    tl[c0 + 3][row] = a.w ? (unsigned char)t.w : (unsigned char)2;
  }
  __syncthreads();
  const int rt0 = row0 >> 4;
#pragma unroll
  for (int j = 0; j < 4; ++j) {
    int idx = j * 256 + tid;
    int nl = idx >> 4;          // 0..63
    int rem = idx & 15;
    int rtl = rem >> 2;         // 0..3
    int q = rem & 3;            // 0..3
    uchar4 v = *(const uchar4*)&tl[nl][rtl * 16 + q * 4];
    *(uchar4*)(tagsQ + ((size_t)(rt0 + rtl) * 1024 + n0 + nl) * 16 + q * 4) = v;
  }
}

__device__ void job_ekev(int g, const float* __restrict__ Wk,
                         const float* __restrict__ Wv, const float* __restrict__ E,
                         float* __restrict__ ek, float* __restrict__ ev) {
  const int tid = threadIdx.x;
  const int bx = g & 7, by = g >> 3;
  const int c = tid >> 3, kseg = tid & 7;
  const int col = bx * 32 + c;
  const float* W = by ? Wv : Wk;
  float* outp = by ? ev : ek;
  const float* wrow = W + (size_t)col * D + kseg * 32;
  const float* e0p = E + kseg * 32;
  const float* e1p = E + D + kseg * 32;
  float p0 = 0.f, p1 = 0.f;
#pragma unroll
  for (int i = 0; i < 8; ++i) {
    float4 w4 = *(const float4*)(wrow + i * 4);
    float4 a4 = *(const float4*)(e0p + i * 4);
    float4 b4 = *(const float4*)(e1p + i * 4);
    p0 += w4.x * a4.x + w4.y * a4.y + w4.z * a4.z + w4.w * a4.w;
    p1 += w4.x * b4.x + w4.y * b4.y + w4.z * b4.z + w4.w * b4.w;
  }
#pragma unroll
  for (int off = 1; off <= 4; off <<= 1) {
    p0 += __shfl_xor(p0, off);
    p1 += __shfl_xor(p1, off);
  }
  if (kseg == 0) { outp[col] = p0; outp[D + col] = p1; }
}

__device__ void job_wo(int g, const float* __restrict__ Wo,
                       unsigned short* __restrict__ Wob) {
  const int tid = threadIdx.x;
  const int base = g * 4096;
#pragma unroll
  for (int half = 0; half < 2; ++half) {
    int e0 = base + half * 2048 + tid * 8;
    float4 f0 = *(const float4*)(Wo + e0);
    float4 f1 = *(const float4*)(Wo + e0 + 4);
    uint4 o;
    o.x = pack2(f0.x, f0.y);
    o.y = pack2(f0.z, f0.w);
    o.z = pack2(f1.x, f1.y);
    o.w = pack2(f1.z, f1.w);
    *(uint4*)(Wob + e0) = o;
  }
}

// ---------------------------------------------------------------------------
// Single fused kernel, plain launch, 512 blocks x 256 threads, 2 blocks/CU.
// Phase A: 1056 jobs. Barrier. Phase B: attention. Barrier. Phase C: out-proj.
// ---------------------------------------------------------------------------
__global__ __launch_bounds__(256, 2) void fused_all(
    const float* __restrict__ ht, const float* __restrict__ hn,
    const int* __restrict__ adj, const int* __restrict__ ety,
    const float* __restrict__ Wq, const float* __restrict__ bq,
    const float* __restrict__ Wk, const float* __restrict__ bk,
    const float* __restrict__ Wv, const float* __restrict__ bv,
    const float* __restrict__ Wo, const float* __restrict__ bo,
    const float* __restrict__ E,
    unsigned char* __restrict__ tagsQ, float* __restrict__ ek,
    float* __restrict__ ev, unsigned short* __restrict__ Qh,
    unsigned short* __restrict__ Kh, unsigned short* __restrict__ Vt,
    unsigned short* __restrict__ Wob, unsigned short* __restrict__ Ob,
    float* __restrict__ out, unsigned* __restrict__ bar) {
  __shared__ __align__(16) char smem[42240];
  const int blk = blockIdx.x;
  const int tid = threadIdx.x;

  // ================= PHASE A =================
  {
    int j0 = blk;
    int j1 = blk + 512;
    if (j0 < 768) job_qkv(j0, smem, ht, hn, Wq, bq, Wk, bk, Wv, bv, Qh, Kh, Vt);
    else job_tags(j0 - 768, smem, adj, ety, tagsQ);
    __syncthreads();
    if (j1 < 768) job_qkv(j1, smem, ht, hn, Wq, bq, Wk, bk, Wv, bv, Qh, Kh, Vt);
    else job_tags(j1 - 768, smem, adj, ety, tagsQ);
    if (blk < 16) job_ekev(blk, Wk, Wv, E, ek, ev);
    else if (blk < 32) job_wo(blk - 16, Wo, Wob);
  }
  grid_barrier(bar, 512u);

  // ================= PHASE B: attention =================
  {
    unsigned short (*P)[16][136] = (unsigned short(*)[16][136])smem;  // 8704 B
    float* qe_s = (float*)(smem + 8704);    // [16][2]
    float* den_p = (float*)(smem + 8832);   // [4][16]
    float* s1_p = (float*)(smem + 9088);    // [4][16]
    float* accb = (float*)(smem + 9344);    // [2][16][17]

    const int h = blk >> 6;
    const int rt = blk & 63;
    const int row0 = rt * 16;
    const int wid = tid >> 6;
    const int lane = tid & 63;
    const int quad = lane >> 4, l16 = lane & 15;
    const int nt = wid & 1, kc = wid >> 1;
    const float scale = 0.17677669529663687f;  // 1/sqrt(32)

    const unsigned short* Qbase = Qh + (size_t)h * 32768;
    const unsigned short* Kbase = Kh + (size_t)h * 32768;
    const unsigned short* Vbase = Vt + (size_t)h * 32768;
    const unsigned char* tagbase = tagsQ + (size_t)rt * 1024 * 16;

    short8 aQ = *(const short8*)(Qbase + (size_t)(row0 + l16) * 32 + quad * 8);

    if (tid < 32) {
      int r = tid >> 1, tg = tid & 1;
      const unsigned short* qp = Qbase + (size_t)(row0 + r) * 32;
      const float* ep = ek + tg * D + h * DH;
      float s = 0.f;
#pragma unroll
      for (int dd = 0; dd < 32; ++dd) s += bf2f(qp[dd]) * ep[dd];
      qe_s[r * 2 + tg] = s * scale;
    }
    __syncthreads();

    float den_loc[4] = {0.f, 0.f, 0.f, 0.f};
    float s1_loc[4] = {0.f, 0.f, 0.f, 0.f};
    f32x4 acc0 = {0.f, 0.f, 0.f, 0.f};
    f32x4 acc1 = {0.f, 0.f, 0.f, 0.f};
    const f32x4 zero = {0.f, 0.f, 0.f, 0.f};

    for (int t = 0; t < 8; ++t) {
      const int n0 = t * 128;
      const int buf = t & 1;
      const int nc0 = wid * 16;
      const int nc1 = 64 + wid * 16;
      short8 bK0 = *(const short8*)(Kbase + (size_t)(n0 + nc0 + l16) * 32 + quad * 8);
      short8 bK1 = *(const short8*)(Kbase + (size_t)(n0 + nc1 + l16) * 32 + quad * 8);
      uchar4 tg40 = *(const uchar4*)(tagbase + (size_t)(n0 + nc0 + l16) * 16 + quad * 4);
      uchar4 tg41 = *(const uchar4*)(tagbase + (size_t)(n0 + nc1 + l16) * 16 + quad * 4);
      short8 bV0 = *(const short8*)(Vbase + (size_t)(nt * 16 + l16) * 1024 + n0 + kc * 64 + quad * 8);
      short8 bV1 = *(const short8*)(Vbase + (size_t)(nt * 16 + l16) * 1024 + n0 + kc * 64 + 32 + quad * 8);

      f32x4 sc0 = __builtin_amdgcn_mfma_f32_16x16x32_bf16(aQ, bK0, zero, 0, 0, 0);
      f32x4 sc1 = __builtin_amdgcn_mfma_f32_16x16x32_bf16(aQ, bK1, zero, 0, 0, 0);

      const unsigned char tga0[4] = {tg40.x, tg40.y, tg40.z, tg40.w};
      const unsigned char tga1[4] = {tg41.x, tg41.y, tg41.z, tg41.w};
#pragma unroll
      for (int r = 0; r < 4; ++r) {
        const int row = quad * 4 + r;
        const int tg = tga0[r];
        float e = 0.f;
        if (tg != 2) e = __expf(fmaf(sc0[r], scale, qe_s[row * 2 + tg]));
        den_loc[r] += e;
        s1_loc[r] += (tg == 1) ? e : 0.f;
        P[buf][row][nc0 + l16] = f2bf(e);
      }
#pragma unroll
      for (int r = 0; r < 4; ++r) {
        const int row = quad * 4 + r;
        const int tg = tga1[r];
        float e = 0.f;
        if (tg != 2) e = __expf(fmaf(sc1[r], scale, qe_s[row * 2 + tg]));
        den_loc[r] += e;
        s1_loc[r] += (tg == 1) ? e : 0.f;
        P[buf][row][nc1 + l16] = f2bf(e);
      }
      __syncthreads();
      short8 aP0 = *(const short8*)&P[buf][l16][kc * 64 + quad * 8];
      short8 aP1 = *(const short8*)&P[buf][l16][kc * 64 + 32 + quad * 8];
      acc0 = __builtin_amdgcn_mfma_f32_16x16x32_bf16(aP0, bV0, acc0, 0, 0, 0);
      acc1 = __builtin_amdgcn_mfma_f32_16x16x32_bf16(aP1, bV1, acc1, 0, 0, 0);
    }
    f32x4 acc = acc0 + acc1;

#pragma unroll
    for (int r = 0; r < 4; ++r) {
#pragma unroll
      for (int off = 1; off <= 8; off <<= 1) {
        den_loc[r] += __shfl_xor(den_loc[r], off);
        s1_loc[r] += __shfl_xor(s1_loc[r], off);
      }
    }
    if (l16 == 0) {
#pragma unroll
      for (int r = 0; r < 4; ++r) {
        den_p[wid * 16 + quad * 4 + r] = den_loc[r];
        s1_p[wid * 16 + quad * 4 + r] = s1_loc[r];
      }
    }
    if (kc == 1) {
#pragma unroll
      for (int r = 0; r < 4; ++r) accb[(nt * 16 + quad * 4 + r) * 17 + l16] = acc[r];
    }
    __syncthreads();
    if (kc == 0) {
      const int d = nt * 16 + l16;
      const float e0v = ev[h * DH + d];
      const float e1v = ev[D + h * DH + d];
#pragma unroll
      for (int r = 0; r < 4; ++r) {
        const int row = quad * 4 + r;
        float den = den_p[row] + den_p[16 + row] + den_p[32 + row] + den_p[48 + row];
        float s1 = s1_p[row] + s1_p[16 + row] + s1_p[32 + row] + s1_p[48 + row];
        float s0 = den - s1;
        float inv = den > 0.f ? 1.f / den : 0.f;
        float o = (acc[r] + accb[(nt * 16 + row) * 17 + l16] + s1 * e1v + s0 * e0v) * inv;
        Ob[(size_t)(row0 + row) * D + h * DH + d] = f2bf(o);
      }
    }
  }
  grid_barrier(bar, 1024u);

  // ================= PHASE C: out-projection =================
  if (blk < 256) {
    const int lane = tid & 63;
    const int wid = tid >> 6;
    const int quad = lane >> 4, l16 = lane & 15;
    const int m0 = (blk & 63) * 16;
    const int n0 = (blk >> 6) * 64 + wid * 16;
    f32x4 acc0 = {0.f, 0.f, 0.f, 0.f};
    f32x4 acc1 = {0.f, 0.f, 0.f, 0.f};
#pragma unroll
    for (int k0 = 0; k0 < 128; k0 += 32) {
      short8 a = *(const short8*)(Ob + (size_t)(m0 + l16) * 256 + k0 + quad * 8);
      short8 b = *(const short8*)(Wob + (size_t)(n0 + l16) * 256 + k0 + quad * 8);
      acc0 = __builtin_amdgcn_mfma_f32_16x16x32_bf16(a, b, acc0, 0, 0, 0);
    }
#pragma unroll
    for (int k0 = 128; k0 < 256; k0 += 32) {
      short8 a = *(const short8*)(Ob + (size_t)(m0 + l16) * 256 + k0 + quad * 8);
      short8 b = *(const short8*)(Wob + (size_t)(n0 + l16) * 256 + k0 + quad * 8);
      acc1 = __builtin_amdgcn_mfma_f32_16x16x32_bf16(a, b, acc1, 0, 0, 0);
    }
    f32x4 acc = acc0 + acc1;
    const int col = n0 + l16;
    const float bia = bo[col];
#pragma unroll
    for (int r = 0; r < 4; ++r) {
      out[(size_t)(m0 + quad * 4 + r) * 256 + col] = acc[r] + bia;
    }
  }
}

// ===========================================================================
extern "C" void kernel_launch(void* const* d_in, const int* in_sizes, int n_in,
                              void* d_out, int out_size, void* d_ws, size_t ws_size,
                              hipStream_t stream) {
  const float* h_target = (const float*)d_in[0];
  const float* h_neigh  = (const float*)d_in[1];
  const int*   adjacency= (const int*)d_in[2];
  const int*   edge_ty  = (const int*)d_in[3];
  const float* Wq = (const float*)d_in[4];
  const float* bq = (const float*)d_in[5];
  const float* Wk = (const float*)d_in[6];
  const float* bk = (const float*)d_in[7];
  const float* Wv = (const float*)d_in[8];
  const float* bv = (const float*)d_in[9];
  const float* Wo = (const float*)d_in[10];
  const float* bo = (const float*)d_in[11];
  const float* E  = (const float*)d_in[12];
  float* out = (float*)d_out;

  unsigned char* wsb = (unsigned char*)d_ws;
  unsigned char*  tagsQ = wsb;                                 // 1 MB
  unsigned short* Qh  = (unsigned short*)(wsb + 0x100000);     // 512 KB
  unsigned short* Kh  = (unsigned short*)(wsb + 0x180000);     // 512 KB
  unsigned short* Vt  = (unsigned short*)(wsb + 0x200000);     // 512 KB
  unsigned short* Ob  = (unsigned short*)(wsb + 0x280000);     // 512 KB
  unsigned short* Wob = (unsigned short*)(wsb + 0x300000);     // 128 KB
  float* ek = (float*)(wsb + 0x320000);                        // 2 KB
  float* ev = (float*)(wsb + 0x320800);                        // 2 KB
  unsigned* bar = (unsigned*)(wsb + 0x321000);                 // barrier ctr

  // ws is poisoned to 0xAA before every launch: zero the barrier counter.
  hipMemsetAsync(bar, 0, 128, stream);

  fused_all<<<512, 256, 0, stream>>>(
      h_target, h_neigh, adjacency, edge_ty, Wq, bq, Wk, bk, Wv, bv, Wo, bo, E,
      tagsQ, ek, ev, Qh, Kh, Vt, Wob, Ob, out, bar);
}

// Round 8
// 109.292 us; speedup vs baseline: 2.0269x; 2.0269x over previous
//
#include <hip/hip_runtime.h>
#include <math.h>

#define BT 1024
#define BN 1024
#define D  256
#define H  8
#define DH 32

typedef __attribute__((ext_vector_type(8))) short short8;
typedef __attribute__((ext_vector_type(4))) float f32x4;

__device__ __forceinline__ unsigned short f2bf(float x) {
  union { float f; unsigned int u; } v; v.f = x;
  unsigned int r = v.u + 0x7fffu + ((v.u >> 16) & 1u);
  return (unsigned short)(r >> 16);
}
__device__ __forceinline__ float bf2f(unsigned short u) {
  union { unsigned int u; float f; } v; v.u = ((unsigned int)u) << 16;
  return v.f;
}
__device__ __forceinline__ unsigned pack2(float a, float b) {
  return (unsigned)f2bf(a) | ((unsigned)f2bf(b) << 16);
}

// ===========================================================================
// Dispatch 1: blocks [0,768)    qkv GEMMs (fp32->bf16 in LDS staging)
//             blocks [768,1024) tag pack row-major: tags[row][n]=adj?et:2 (u8)
//             blocks [1024,1040) ek/ev = E @ {Wk,Wv}^T
//             blocks [1040,1056) Wo fp32 -> bf16
// ===========================================================================
__global__ __launch_bounds__(256) void fused_prep_qkv(
    const float* __restrict__ ht, const float* __restrict__ hn,
    const int* __restrict__ adj, const int* __restrict__ ety,
    const float* __restrict__ Wq, const float* __restrict__ bq,
    const float* __restrict__ Wk, const float* __restrict__ bk,
    const float* __restrict__ Wv, const float* __restrict__ bv,
    const float* __restrict__ Wo, const float* __restrict__ E,
    unsigned char* __restrict__ tags, float* __restrict__ ek,
    float* __restrict__ ev, unsigned short* __restrict__ Qh,
    unsigned short* __restrict__ Kh, unsigned short* __restrict__ Vt,
    unsigned short* __restrict__ Wob) {
  const int blk = blockIdx.x;
  const int tid = threadIdx.x;

  if (blk < 768) {
    const int gm = blk >> 8;           // 0=Q, 1=K, 2=V
    const int rem = blk & 255;
    const int m0 = (rem & 63) * 16;
    const int nb0 = (rem >> 6) * 64;
    const float* X = (gm == 0) ? ht : hn;
    const float* W = (gm == 0) ? Wq : (gm == 1) ? Wk : Wv;
    const float* bias = (gm == 0) ? bq : (gm == 1) ? bk : bv;

    __shared__ unsigned short als[16][264];
    __shared__ unsigned short bls[64][264];

    const int c = (tid & 15) * 16;
    {
      int row = tid >> 4;
      const float* s = X + (size_t)(m0 + row) * D + c;
      uint4 u0, u1;
      float4 f;
      f = *(const float4*)(s + 0);  u0.x = pack2(f.x, f.y); u0.y = pack2(f.z, f.w);
      f = *(const float4*)(s + 4);  u0.z = pack2(f.x, f.y); u0.w = pack2(f.z, f.w);
      f = *(const float4*)(s + 8);  u1.x = pack2(f.x, f.y); u1.y = pack2(f.z, f.w);
      f = *(const float4*)(s + 12); u1.z = pack2(f.x, f.y); u1.w = pack2(f.z, f.w);
      *(uint4*)&als[row][c] = u0;
      *(uint4*)&als[row][c + 8] = u1;
    }
#pragma unroll
    for (int j = 0; j < 4; ++j) {
      int row = j * 16 + (tid >> 4);
      const float* s = W + (size_t)(nb0 + row) * D + c;
      uint4 u0, u1;
      float4 f;
      f = *(const float4*)(s + 0);  u0.x = pack2(f.x, f.y); u0.y = pack2(f.z, f.w);
      f = *(const float4*)(s + 4);  u0.z = pack2(f.x, f.y); u0.w = pack2(f.z, f.w);
      f = *(const float4*)(s + 8);  u1.x = pack2(f.x, f.y); u1.y = pack2(f.z, f.w);
      f = *(const float4*)(s + 12); u1.z = pack2(f.x, f.y); u1.w = pack2(f.z, f.w);
      *(uint4*)&bls[row][c] = u0;
      *(uint4*)&bls[row][c + 8] = u1;
    }
    __syncthreads();

    const int lane = tid & 63, wid = tid >> 6;
    const int quad = lane >> 4, l16 = lane & 15;
    f32x4 acc0 = {0.f, 0.f, 0.f, 0.f};
    f32x4 acc1 = {0.f, 0.f, 0.f, 0.f};
#pragma unroll
    for (int k0 = 0; k0 < 128; k0 += 32) {
      short8 a = *(const short8*)&als[l16][k0 + quad * 8];
      short8 b = *(const short8*)&bls[wid * 16 + l16][k0 + quad * 8];
      acc0 = __builtin_amdgcn_mfma_f32_16x16x32_bf16(a, b, acc0, 0, 0, 0);
    }
#pragma unroll
    for (int k0 = 128; k0 < 256; k0 += 32) {
      short8 a = *(const short8*)&als[l16][k0 + quad * 8];
      short8 b = *(const short8*)&bls[wid * 16 + l16][k0 + quad * 8];
      acc1 = __builtin_amdgcn_mfma_f32_16x16x32_bf16(a, b, acc1, 0, 0, 0);
    }
    f32x4 acc = acc0 + acc1;

    const int col = nb0 + wid * 16 + l16;
    const float bia = bias[col];
    const int h = col >> 5, d = col & 31;
    if (gm == 2) {
      uint2 o;
      o.x = pack2(acc[0] + bia, acc[1] + bia);
      o.y = pack2(acc[2] + bia, acc[3] + bia);
      *(uint2*)(Vt + (size_t)h * 32768 + (size_t)d * 1024 + m0 + quad * 4) = o;
    } else {
      unsigned short* dst = (gm == 0) ? Qh : Kh;
#pragma unroll
      for (int r = 0; r < 4; ++r) {
        int row = m0 + quad * 4 + r;
        dst[(size_t)h * 32768 + (size_t)row * 32 + d] = f2bf(acc[r] + bia);
      }
    }
  } else if (blk < 1024) {
    // row-major tag pack, fully coalesced
    const int local = blk - 768;
#pragma unroll
    for (int i = 0; i < 4; ++i) {
      int idx = local * 1024 + i * 256 + tid;  // int4 units
      int4 a = ((const int4*)adj)[idx];
      int4 t = ((const int4*)ety)[idx];
      uchar4 o;
      o.x = a.x ? (unsigned char)t.x : (unsigned char)2;
      o.y = a.y ? (unsigned char)t.y : (unsigned char)2;
      o.z = a.z ? (unsigned char)t.z : (unsigned char)2;
      o.w = a.w ? (unsigned char)t.w : (unsigned char)2;
      ((uchar4*)tags)[idx] = o;
    }
  } else if (blk < 1040) {
    const int g = blk - 1024;
    const int bx = g & 7, by = g >> 3;
    const int c = tid >> 3, kseg = tid & 7;
    const int col = bx * 32 + c;
    const float* W = by ? Wv : Wk;
    float* outp = by ? ev : ek;
    const float* wrow = W + (size_t)col * D + kseg * 32;
    const float* e0p = E + kseg * 32;
    const float* e1p = E + D + kseg * 32;
    float p0 = 0.f, p1 = 0.f;
#pragma unroll
    for (int i = 0; i < 8; ++i) {
      float4 w4 = *(const float4*)(wrow + i * 4);
      float4 a4 = *(const float4*)(e0p + i * 4);
      float4 b4 = *(const float4*)(e1p + i * 4);
      p0 += w4.x * a4.x + w4.y * a4.y + w4.z * a4.z + w4.w * a4.w;
      p1 += w4.x * b4.x + w4.y * b4.y + w4.z * b4.z + w4.w * b4.w;
    }
#pragma unroll
    for (int off = 1; off <= 4; off <<= 1) {
      p0 += __shfl_xor(p0, off);
      p1 += __shfl_xor(p1, off);
    }
    if (kseg == 0) { outp[col] = p0; outp[D + col] = p1; }
  } else {
    const int g = blk - 1040;
    const int base = g * 4096;
#pragma unroll
    for (int half = 0; half < 2; ++half) {
      int e0 = base + half * 2048 + tid * 8;
      float4 f0 = *(const float4*)(Wo + e0);
      float4 f1 = *(const float4*)(Wo + e0 + 4);
      uint4 o;
      o.x = pack2(f0.x, f0.y);
      o.y = pack2(f0.z, f0.w);
      o.z = pack2(f1.x, f1.y);
      o.w = pack2(f1.z, f1.w);
      *(uint4*)(Wob + e0) = o;
    }
  }
}

// ===========================================================================
// attn v3: transposed-score MFMA, barrier-free main loop.
// Block = 512 threads = 8 independent waves; block handles (16 rows, 1 head);
// wave w owns neighbors [w*128, w*128+128) in 4 chunks of 32.
// Per chunk: S^T = mfma(A=K, B=Q) -> lane holds (n=q*4+r, row=l16).
//   exp (tags row-major uchar4) -> P[l16][n] via 2x ds_write_b64 (contiguous
//   4-run in n) -> B-frag read ds_read_b128 -> PV = mfma(A=Vt, B=P):
//   acc lane holds (d=q*4+r, row=l16). No __syncthreads in loop.
// End: shfl-reduce den/s1 over quads, one LDS combine across 8 waves,
// wave 0 does epilogue.
// ===========================================================================
__global__ __launch_bounds__(512, 4) void attn_mfma(
    const unsigned short* __restrict__ Qh, const unsigned short* __restrict__ Kh,
    const unsigned short* __restrict__ Vt,
    const float* __restrict__ ek, const float* __restrict__ ev,
    const unsigned char* __restrict__ tags, unsigned short* __restrict__ Ob) {
  __shared__ __align__(16) unsigned short P[8][16][40];  // per-wave, 10240 B
  __shared__ float comb[8 * 64 * 11];                    // 22528 B

  const int h = blockIdx.y;
  const int row0 = blockIdx.x * 16;
  const int tid = threadIdx.x;
  const int w = tid >> 6;
  const int lane = tid & 63;
  const int q = lane >> 4, l16 = lane & 15;
  const float scale = 0.17677669529663687f;  // 1/sqrt(32)

  const unsigned short* Qbase = Qh + (size_t)h * 32768;
  const unsigned short* Kbase = Kh + (size_t)h * 32768;
  const unsigned short* Vbase = Vt + (size_t)h * 32768;

  // B-operand: Q fragment, lane j=l16 -> target row, k=q*8..q*8+7 (d)
  short8 bQ = *(const short8*)(Qbase + (size_t)(row0 + l16) * 32 + q * 8);

  // qe[row][tg] = scale * q_row . ek[tg] ; computed redundantly per wave.
  float qe_mine = 0.f;
  {
    int r = (lane >> 1) & 15, tg = lane & 1;
    const unsigned short* qp = Qbase + (size_t)(row0 + r) * 32;
    const float* ep = ek + tg * D + h * DH;
#pragma unroll
    for (int dd = 0; dd < 32; ++dd) qe_mine += bf2f(qp[dd]) * ep[dd];
    qe_mine *= scale;
  }
  const float qe0 = __shfl(qe_mine, l16 * 2, 64);      // qe[row=l16][0]
  const float qe1 = __shfl(qe_mine, l16 * 2 + 1, 64);  // qe[row=l16][1]

  float den_loc = 0.f, s1_loc = 0.f;
  f32x4 acc0 = {0.f, 0.f, 0.f, 0.f};
  f32x4 acc1 = {0.f, 0.f, 0.f, 0.f};
  const f32x4 zero = {0.f, 0.f, 0.f, 0.f};
  unsigned short* Pw = &P[w][0][0];

  for (int cch = 0; cch < 4; ++cch) {
    const int nb = w * 128 + cch * 32;
    // A-operand K frags: lane i=l16 -> neighbor n, k=q*8 (d)
    short8 aK0 = *(const short8*)(Kbase + (size_t)(nb + l16) * 32 + q * 8);
    short8 aK1 = *(const short8*)(Kbase + (size_t)(nb + 16 + l16) * 32 + q * 8);
    // A-operand V^T frags: lane i=l16 -> d, k=q*8 (n within chunk)
    short8 vA0 = *(const short8*)(Vbase + (size_t)l16 * 1024 + nb + q * 8);
    short8 vA1 = *(const short8*)(Vbase + (size_t)(16 + l16) * 1024 + nb + q * 8);
    // tags row-major: (row=l16, n = nb + q*4 + r)
    uchar4 t0 = *(const uchar4*)(tags + (size_t)(row0 + l16) * BN + nb + q * 4);
    uchar4 t1 = *(const uchar4*)(tags + (size_t)(row0 + l16) * BN + nb + 16 + q * 4);

    f32x4 sc0 = __builtin_amdgcn_mfma_f32_16x16x32_bf16(aK0, bQ, zero, 0, 0, 0);
    f32x4 sc1 = __builtin_amdgcn_mfma_f32_16x16x32_bf16(aK1, bQ, zero, 0, 0, 0);

    const unsigned char ta0[4] = {t0.x, t0.y, t0.z, t0.w};
    const unsigned char ta1[4] = {t1.x, t1.y, t1.z, t1.w};
    float e0[4], e1[4];
#pragma unroll
    for (int r = 0; r < 4; ++r) {
      const int tg = ta0[r];
      float e = 0.f;
      if (tg != 2) e = __expf(fmaf(sc0[r], scale, tg ? qe1 : qe0));
      e0[r] = e;
      den_loc += e;
      s1_loc += (tg == 1) ? e : 0.f;
    }
#pragma unroll
    for (int r = 0; r < 4; ++r) {
      const int tg = ta1[r];
      float e = 0.f;
      if (tg != 2) e = __expf(fmaf(sc1[r], scale, tg ? qe1 : qe0));
      e1[r] = e;
      den_loc += e;
      s1_loc += (tg == 1) ? e : 0.f;
    }
    // P[row=l16][n-local]: contiguous 4-runs -> 8B stores
    uint2 w0, w1;
    w0.x = pack2(e0[0], e0[1]); w0.y = pack2(e0[2], e0[3]);
    w1.x = pack2(e1[0], e1[1]); w1.y = pack2(e1[2], e1[3]);
    *(uint2*)&Pw[l16 * 40 + q * 4] = w0;
    *(uint2*)&Pw[l16 * 40 + 16 + q * 4] = w1;
    // B-operand P frag: lane j=l16=row, k=q*8 (n) — same-wave roundtrip,
    // compiler inserts lgkmcnt; no barrier needed.
    short8 pB = *(const short8*)&Pw[l16 * 40 + q * 8];
    acc0 = __builtin_amdgcn_mfma_f32_16x16x32_bf16(vA0, pB, acc0, 0, 0, 0);
    acc1 = __builtin_amdgcn_mfma_f32_16x16x32_bf16(vA1, pB, acc1, 0, 0, 0);
  }

  // den/s1: sum over quads -> every lane holds row=l16 totals for this wave
  den_loc += __shfl_xor(den_loc, 16);
  den_loc += __shfl_xor(den_loc, 32);
  s1_loc += __shfl_xor(s1_loc, 16);
  s1_loc += __shfl_xor(s1_loc, 32);

  // cross-wave combine
  {
    float* cw = &comb[(w * 64 + lane) * 11];
    cw[0] = acc0[0]; cw[1] = acc0[1]; cw[2] = acc0[2]; cw[3] = acc0[3];
    cw[4] = acc1[0]; cw[5] = acc1[1]; cw[6] = acc1[2]; cw[7] = acc1[3];
    cw[8] = den_loc; cw[9] = s1_loc;
  }
  __syncthreads();
  if (w == 0) {
    float a0[4] = {0.f, 0.f, 0.f, 0.f}, a1[4] = {0.f, 0.f, 0.f, 0.f};
    float dn = 0.f, s1 = 0.f;
#pragma unroll
    for (int ww = 0; ww < 8; ++ww) {
      const float* cr = &comb[(ww * 64 + lane) * 11];
#pragma unroll
      for (int r = 0; r < 4; ++r) { a0[r] += cr[r]; a1[r] += cr[4 + r]; }
      dn += cr[8];
      s1 += cr[9];
    }
    const float s0 = dn - s1;
    const float inv = dn > 0.f ? 1.f / dn : 0.f;
    const float4 ev0a = *(const float4*)(ev + h * DH + q * 4);
    const float4 ev1a = *(const float4*)(ev + D + h * DH + q * 4);
    const float4 ev0b = *(const float4*)(ev + h * DH + 16 + q * 4);
    const float4 ev1b = *(const float4*)(ev + D + h * DH + 16 + q * 4);
    float oa[4], ob[4];
    oa[0] = (a0[0] + s1 * ev1a.x + s0 * ev0a.x) * inv;
    oa[1] = (a0[1] + s1 * ev1a.y + s0 * ev0a.y) * inv;
    oa[2] = (a0[2] + s1 * ev1a.z + s0 * ev0a.z) * inv;
    oa[3] = (a0[3] + s1 * ev1a.w + s0 * ev0a.w) * inv;
    ob[0] = (a1[0] + s1 * ev1b.x + s0 * ev0b.x) * inv;
    ob[1] = (a1[1] + s1 * ev1b.y + s0 * ev0b.y) * inv;
    ob[2] = (a1[2] + s1 * ev1b.z + s0 * ev0b.z) * inv;
    ob[3] = (a1[3] + s1 * ev1b.w + s0 * ev0b.w) * inv;
    uint2 u0, u1;
    u0.x = pack2(oa[0], oa[1]); u0.y = pack2(oa[2], oa[3]);
    u1.x = pack2(ob[0], ob[1]); u1.y = pack2(ob[2], ob[3]);
    unsigned short* dst = Ob + (size_t)(row0 + l16) * D + h * DH + q * 4;
    *(uint2*)dst = u0;          // d = q*4 .. q*4+3
    *(uint2*)(dst + 16) = u1;   // d = 16+q*4 ..
  }
}

// ===========================================================================
// out = Ob @ Wob^T + bo (fp32 out). Direct global frags, no LDS. grid (64,4).
// ===========================================================================
__global__ __launch_bounds__(256) void proj_out_mfma(
    const unsigned short* __restrict__ Ob, const unsigned short* __restrict__ Wob,
    const float* __restrict__ bo, float* __restrict__ out) {
  const int lane = threadIdx.x & 63;
  const int wid = threadIdx.x >> 6;
  const int quad = lane >> 4, l16 = lane & 15;
  const int m0 = blockIdx.x * 16;
  const int n0 = blockIdx.y * 64 + wid * 16;
  f32x4 acc0 = {0.f, 0.f, 0.f, 0.f};
  f32x4 acc1 = {0.f, 0.f, 0.f, 0.f};
#pragma unroll
  for (int k0 = 0; k0 < 128; k0 += 32) {
    short8 a = *(const short8*)(Ob + (size_t)(m0 + l16) * 256 + k0 + quad * 8);
    short8 b = *(const short8*)(Wob + (size_t)(n0 + l16) * 256 + k0 + quad * 8);
    acc0 = __builtin_amdgcn_mfma_f32_16x16x32_bf16(a, b, acc0, 0, 0, 0);
  }
#pragma unroll
  for (int k0 = 128; k0 < 256; k0 += 32) {
    short8 a = *(const short8*)(Ob + (size_t)(m0 + l16) * 256 + k0 + quad * 8);
    short8 b = *(const short8*)(Wob + (size_t)(n0 + l16) * 256 + k0 + quad * 8);
    acc1 = __builtin_amdgcn_mfma_f32_16x16x32_bf16(a, b, acc1, 0, 0, 0);
  }
  f32x4 acc = acc0 + acc1;
  const int col = n0 + l16;
  const float bia = bo[col];
#pragma unroll
  for (int r = 0; r < 4; ++r) {
    out[(size_t)(m0 + quad * 4 + r) * 256 + col] = acc[r] + bia;
  }
}

// ===========================================================================
extern "C" void kernel_launch(void* const* d_in, const int* in_sizes, int n_in,
                              void* d_out, int out_size, void* d_ws, size_t ws_size,
                              hipStream_t stream) {
  const float* h_target = (const float*)d_in[0];
  const float* h_neigh  = (const float*)d_in[1];
  const int*   adjacency= (const int*)d_in[2];
  const int*   edge_ty  = (const int*)d_in[3];
  const float* Wq = (const float*)d_in[4];
  const float* bq = (const float*)d_in[5];
  const float* Wk = (const float*)d_in[6];
  const float* bk = (const float*)d_in[7];
  const float* Wv = (const float*)d_in[8];
  const float* bv = (const float*)d_in[9];
  const float* Wo = (const float*)d_in[10];
  const float* bo = (const float*)d_in[11];
  const float* E  = (const float*)d_in[12];
  float* out = (float*)d_out;

  unsigned char* wsb = (unsigned char*)d_ws;
  unsigned char*  tags = wsb;                                  // 1 MB
  unsigned short* Qh  = (unsigned short*)(wsb + 0x100000);     // 512 KB
  unsigned short* Kh  = (unsigned short*)(wsb + 0x180000);     // 512 KB
  unsigned short* Vt  = (unsigned short*)(wsb + 0x200000);     // 512 KB
  unsigned short* Ob  = (unsigned short*)(wsb + 0x280000);     // 512 KB
  unsigned short* Wob = (unsigned short*)(wsb + 0x300000);     // 128 KB
  float* ek = (float*)(wsb + 0x320000);                        // 2 KB
  float* ev = (float*)(wsb + 0x320800);                        // 2 KB

  fused_prep_qkv<<<1056, 256, 0, stream>>>(
      h_target, h_neigh, adjacency, edge_ty, Wq, bq, Wk, bk, Wv, bv, Wo, E,
      tags, ek, ev, Qh, Kh, Vt, Wob);
  attn_mfma<<<dim3(64, 8), 512, 0, stream>>>(Qh, Kh, Vt, ek, ev, tags, Ob);
  proj_out_mfma<<<dim3(64, 4), 256, 0, stream>>>(Ob, Wob, bo, out);
}